// Round 14
// baseline (116.820 us; speedup 1.0000x reference)
//
#include <hip/hip_runtime.h>
#include <hip/hip_fp16.h>

namespace {
constexpr int A_N = 96;
constexpr int U_N = 128;
constexpr int V_N = 128;
constexpr int W_N = 128;
constexpr int H_N = 128;
constexpr int NSTEPS = 128;
constexpr float T_HALF = 89.80256121069154f;
constexpr float DT = 1.4031650189170554f;   // 2*T/NSTEPS
constexpr float INV_DT = 1.0f / DT;
constexpr int PAD = 10;                     // covers range slop + 4-step alignment (<=6 steps ~ 8.5 units)
constexpr int WP = W_N + 2 * PAD;           // 148 padded columns per row
constexpr int ROW_BYTES = WP * 256;         // x-stride in bytes (f16 column = 256 B)
constexpr int RAYS_PER_BLOCK = 8;           // 128-thread blocks
constexpr int BLOCK_THREADS = RAYS_PER_BLOCK * 16;
constexpr int SEGS = 2;
constexpr size_t VOLP_COLS = (size_t)WP * WP;          // 21904 columns
constexpr size_t VOLP_BYTES = VOLP_COLS * 256;         // ~5.61 MB
constexpr size_t SINO = (size_t)U_N * A_N * V_N;       // 1.57M floats
}

// ---- pack two floats -> half2 bits ----
__device__ __forceinline__ unsigned int packh2(float a, float b) {
    return (unsigned int)__half_as_ushort(__float2half_rn(a)) |
           ((unsigned int)__half_as_ushort(__float2half_rn(b)) << 16);
}

// ---- pre-pass: fp32 volume -> padded f16 volume (zero border of PAD cols) ----
__global__ __launch_bounds__(256) void vol_pad_f16(
    const float* __restrict__ vol, unsigned int* __restrict__ volp)
{
    const int idx = blockIdx.x * 256 + threadIdx.x;    // WP*WP*16 threads
    if (idx >= (int)(VOLP_COLS * 16)) return;
    const int zo  = idx & 15;
    const int col = idx >> 4;
    const int yp = col % WP;
    const int xp = col / WP;
    const int x = xp - PAD;
    const int y = yp - PAD;
    uint4 o = make_uint4(0u, 0u, 0u, 0u);
    if ((unsigned)x < 128u && (unsigned)y < 128u) {
        const float* src = vol + (((size_t)x * 128 + y) << 7) + zo * 8;
        const float4 f0 = *(const float4*)(src);
        const float4 f1 = *(const float4*)(src + 4);
        o.x = packh2(f0.x, f0.y);
        o.y = packh2(f0.z, f0.w);
        o.z = packh2(f1.x, f1.y);
        o.w = packh2(f1.z, f1.w);
    }
    *(uint4*)((char*)volp + (size_t)col * 256 + zo * 16) = o;
}

// ---- one bilinear step: base pointer + fractional weights ----
__device__ __forceinline__ const char* step_base(
    const char* volc, int lane16, float i_f, float cv, float sv, float xb, float yb,
    float& fx, float& fy)
{
    const float tf = fmaf(i_f + 0.5f, DT, -T_HALF);
    const float xi = fmaf(tf, cv, xb);
    const float yi = fmaf(tf, sv, yb);
    const float fx0 = floorf(xi);
    const float fy0 = floorf(yi);
    fx = xi - fx0;
    fy = yi - fy0;
    const int x0 = (int)fx0;
    const int y0 = (int)fy0;
    const int base = (((x0 + PAD) * WP + (y0 + PAD)) << 8) + lane16;
    return volc + base;
}

// consume into half2 accumulators
__device__ __forceinline__ void consume_h2(
    const uint4& q00, const uint4& q01, const uint4& q10, const uint4& q11,
    float fx, float fy, __half2& a0, __half2& a1, __half2& a2, __half2& a3)
{
    const float wx0 = 1.f - fx;
    const float wy0 = 1.f - fy;
    const __half2 w00 = __float2half2_rn(wx0 * wy0);  // (x0,y0)
    const __half2 w01 = __float2half2_rn(wx0 * fy);   // (x0,y1)
    const __half2 w10 = __float2half2_rn(fx  * wy0);  // (x1,y0)
    const __half2 w11 = __float2half2_rn(fx  * fy);   // (x1,y1)
    const __half2* h00 = (const __half2*)&q00;
    const __half2* h01 = (const __half2*)&q01;
    const __half2* h10 = (const __half2*)&q10;
    const __half2* h11 = (const __half2*)&q11;
    a0 = __hfma2(w00, h00[0], __hfma2(w01, h01[0], __hfma2(w10, h10[0], __hfma2(w11, h11[0], a0))));
    a1 = __hfma2(w00, h00[1], __hfma2(w01, h01[1], __hfma2(w10, h10[1], __hfma2(w11, h11[1], a1))));
    a2 = __hfma2(w00, h00[2], __hfma2(w01, h01[2], __hfma2(w10, h10[2], __hfma2(w11, h11[2], a2))));
    a3 = __hfma2(w00, h00[3], __hfma2(w01, h01[3], __hfma2(w10, h10[3], __hfma2(w11, h11[3], a3))));
}

// ---- main projector: barrier-free, padded f16 volume, 4-step unrolled (16 loads in flight) ----
__global__ __launch_bounds__(BLOCK_THREADS) void joseph_fwd_inc(
    const unsigned short* __restrict__ volp,
    const float* __restrict__ angles,
    float* __restrict__ dst, float scale)
{
    const int zo  = threadIdx.x & 15;        // 16 z-groups of 8
    const int r   = threadIdx.x >> 4;        // ray in block
    const int u_i = blockIdx.x * RAYS_PER_BLOCK + r;
    const int a   = blockIdx.y;

    const int spseg = NSTEPS / gridDim.z;
    const int i0 = blockIdx.z * spseg;       // multiple of 4 for SEGS in {1,2,4}
    const int i1 = i0 + spseg;

    const float ang = angles[a];
    const float cv = cosf(ang);
    const float sv = sinf(ang);
    const float up = (float)u_i - 63.5f;
    const float xb = fmaf(-up, sv, 63.5f);
    const float yb = fmaf( up, cv, 63.5f);

    // valid-step range: xi,yi in (-1,128); total slop (range + 4-alignment) <= 6 steps < PAD
    float tlo = -2.f * T_HALF, thi = 2.f * T_HALF;
    if (fabsf(cv) > 1e-6f) {
        const float ta = (-1.f - xb) / cv, tb = (128.f - xb) / cv;
        tlo = fmaxf(tlo, fminf(ta, tb));
        thi = fminf(thi, fmaxf(ta, tb));
    } else if (xb <= -1.f || xb >= 128.f) { thi = tlo - 1.f; }
    if (fabsf(sv) > 1e-6f) {
        const float ta = (-1.f - yb) / sv, tb = (128.f - yb) / sv;
        tlo = fmaxf(tlo, fminf(ta, tb));
        thi = fminf(thi, fmaxf(ta, tb));
    } else if (yb <= -1.f || yb >= 128.f) { thi = tlo - 1.f; }
    const int ilo = (int)floorf(fmaf(tlo + T_HALF, INV_DT, -0.5f)) - 1;
    const int ihi = (int)ceilf (fmaf(thi + T_HALF, INV_DT, -0.5f)) + 1;
    int lo = min(max(ilo, i0), i1);
    int hi = min(max(ihi + 1, i0), i1);
    lo &= ~3;                                  // 4-align down (pad-safe)
    hi = (hi + 3) & ~3;                        // 4-align up (spseg mult of 4 -> hi<=i1)

    const char* __restrict__ volc = (const char*)volp;
    const int lane16 = zo << 4;

    float accf[8];
#pragma unroll
    for (int k = 0; k < 8; ++k) accf[k] = 0.f;
    const __half2 hz = __float2half2_rn(0.f);

    for (int i = lo; i < hi; i += 4) {
        float fxA, fyA, fxB, fyB, fxC, fyC, fxD, fyD;
        const char* pA = step_base(volc, lane16, (float)i,       cv, sv, xb, yb, fxA, fyA);
        const char* pB = step_base(volc, lane16, (float)(i + 1), cv, sv, xb, yb, fxB, fyB);
        const char* pC = step_base(volc, lane16, (float)(i + 2), cv, sv, xb, yb, fxC, fyC);
        const char* pD = step_base(volc, lane16, (float)(i + 3), cv, sv, xb, yb, fxD, fyD);

        // issue all 16 loads before consuming any
        const uint4 qA00 = *(const uint4*)(pA);
        const uint4 qA01 = *(const uint4*)(pA + 256);
        const uint4 qA10 = *(const uint4*)(pA + ROW_BYTES);
        const uint4 qA11 = *(const uint4*)(pA + ROW_BYTES + 256);
        const uint4 qB00 = *(const uint4*)(pB);
        const uint4 qB01 = *(const uint4*)(pB + 256);
        const uint4 qB10 = *(const uint4*)(pB + ROW_BYTES);
        const uint4 qB11 = *(const uint4*)(pB + ROW_BYTES + 256);
        const uint4 qC00 = *(const uint4*)(pC);
        const uint4 qC01 = *(const uint4*)(pC + 256);
        const uint4 qC10 = *(const uint4*)(pC + ROW_BYTES);
        const uint4 qC11 = *(const uint4*)(pC + ROW_BYTES + 256);
        const uint4 qD00 = *(const uint4*)(pD);
        const uint4 qD01 = *(const uint4*)(pD + 256);
        const uint4 qD10 = *(const uint4*)(pD + ROW_BYTES);
        const uint4 qD11 = *(const uint4*)(pD + ROW_BYTES + 256);

        __half2 a0 = hz, a1 = hz, a2 = hz, a3 = hz;
        consume_h2(qA00, qA01, qA10, qA11, fxA, fyA, a0, a1, a2, a3);
        consume_h2(qB00, qB01, qB10, qB11, fxB, fyB, a0, a1, a2, a3);
        consume_h2(qC00, qC01, qC10, qC11, fxC, fyC, a0, a1, a2, a3);
        consume_h2(qD00, qD01, qD10, qD11, fxD, fyD, a0, a1, a2, a3);

        const float2 f0 = __half22float2(a0);
        const float2 f1 = __half22float2(a1);
        const float2 f2 = __half22float2(a2);
        const float2 f3 = __half22float2(a3);
        accf[0] += f0.x; accf[1] += f0.y;
        accf[2] += f1.x; accf[3] += f1.y;
        accf[4] += f2.x; accf[5] += f2.y;
        accf[6] += f3.x; accf[7] += f3.y;
    }

    float* op = dst + (size_t)blockIdx.z * SINO + ((size_t)u_i * A_N + a) * V_N + 8 * zo;
    *(float4*)(op)     = make_float4(accf[0] * scale, accf[1] * scale, accf[2] * scale, accf[3] * scale);
    *(float4*)(op + 4) = make_float4(accf[4] * scale, accf[5] * scale, accf[6] * scale, accf[7] * scale);
}

// ---- reduce: out = (p0+p1) * DT ----
__global__ __launch_bounds__(256) void reduce_segs2(
    const float4* __restrict__ p, float4* __restrict__ out)
{
    const size_t i = (size_t)blockIdx.x * 256 + threadIdx.x;  // SINO/4 threads
    const size_t q = SINO / 4;
    const float4 a = p[i];
    const float4 b = p[i + q];
    out[i] = make_float4((a.x + b.x) * DT, (a.y + b.y) * DT,
                         (a.z + b.z) * DT, (a.w + b.w) * DT);
}

// ---- fallback: fp32 volume, no workspace needed ----
__global__ __launch_bounds__(256) void joseph_fwd_f32(
    const float* __restrict__ vol,
    const float* __restrict__ angles,
    float* __restrict__ out)
{
    const int zo  = threadIdx.x & 15;
    const int r   = threadIdx.x >> 4;
    const int u_i = blockIdx.x * 16 + r;
    const int a   = blockIdx.y;

    const float ang = angles[a];
    const float c = cosf(ang);
    const float s = sinf(ang);
    const float u = (float)u_i - 63.5f;
    const float xb = fmaf(-u, s, 63.5f);
    const float yb = fmaf( u, c, 63.5f);

    const float* volz = vol + 8 * zo;
    float4 accA = make_float4(0.f, 0.f, 0.f, 0.f);
    float4 accB = make_float4(0.f, 0.f, 0.f, 0.f);

    for (int i = 0; i < NSTEPS; ++i) {
        const float t  = fmaf((float)i + 0.5f, DT, -T_HALF);
        const float xi = fmaf(t, c, xb);
        const float yi = fmaf(t, s, yb);
        const float fx0f = floorf(xi);
        const float fy0f = floorf(yi);
        const int x0 = (int)fx0f;
        const int y0 = (int)fy0f;
        const float fx = xi - fx0f;
        const float fy = yi - fy0f;
        const int x1 = x0 + 1;
        const int y1 = y0 + 1;
        const float wx0 = (x0 >= 0 && x0 < W_N) ? (1.f - fx) : 0.f;
        const float wx1 = (x1 >= 0 && x1 < W_N) ? fx : 0.f;
        const float wy0 = (y0 >= 0 && y0 < H_N) ? (1.f - fy) : 0.f;
        const float wy1 = (y1 >= 0 && y1 < H_N) ? fy : 0.f;
        if ((wx0 + wx1) == 0.f || (wy0 + wy1) == 0.f) continue;
        const int cx0 = min(max(x0, 0), W_N - 1);
        const int cx1 = min(max(x1, 0), W_N - 1);
        const int cy0 = min(max(y0, 0), H_N - 1);
        const int cy1 = min(max(y1, 0), H_N - 1);
        const float* p00 = volz + ((cx0 * H_N + cy0) << 7);
        const float* p01 = volz + ((cx1 * H_N + cy0) << 7);
        const float* p10 = volz + ((cx0 * H_N + cy1) << 7);
        const float* p11 = volz + ((cx1 * H_N + cy1) << 7);
        const float4 v00a = *(const float4*)(p00);
        const float4 v00b = *(const float4*)(p00 + 4);
        const float4 v01a = *(const float4*)(p01);
        const float4 v01b = *(const float4*)(p01 + 4);
        const float4 v10a = *(const float4*)(p10);
        const float4 v10b = *(const float4*)(p10 + 4);
        const float4 v11a = *(const float4*)(p11);
        const float4 v11b = *(const float4*)(p11 + 4);
        const float w00 = wx0 * wy0, w01 = wx1 * wy0, w10 = wx0 * wy1, w11 = wx1 * wy1;
        accA.x = fmaf(w00, v00a.x, fmaf(w01, v01a.x, fmaf(w10, v10a.x, fmaf(w11, v11a.x, accA.x))));
        accA.y = fmaf(w00, v00a.y, fmaf(w01, v01a.y, fmaf(w10, v10a.y, fmaf(w11, v11a.y, accA.y))));
        accA.z = fmaf(w00, v00a.z, fmaf(w01, v01a.z, fmaf(w10, v10a.z, fmaf(w11, v11a.z, accA.z))));
        accA.w = fmaf(w00, v00a.w, fmaf(w01, v01a.w, fmaf(w10, v10a.w, fmaf(w11, v11a.w, accA.w))));
        accB.x = fmaf(w00, v00b.x, fmaf(w01, v01b.x, fmaf(w10, v10b.x, fmaf(w11, v11b.x, accB.x))));
        accB.y = fmaf(w00, v00b.y, fmaf(w01, v01b.y, fmaf(w10, v10b.y, fmaf(w11, v11b.y, accB.y))));
        accB.z = fmaf(w00, v00b.z, fmaf(w01, v01b.z, fmaf(w10, v10b.z, fmaf(w11, v11b.z, accB.z))));
        accB.w = fmaf(w00, v00b.w, fmaf(w01, v01b.w, fmaf(w10, v10b.w, fmaf(w11, v11b.w, accB.w))));
    }

    float* op = out + ((size_t)u_i * A_N + a) * V_N + 8 * zo;
    *(float4*)(op)     = make_float4(accA.x * DT, accA.y * DT, accA.z * DT, accA.w * DT);
    *(float4*)(op + 4) = make_float4(accB.x * DT, accB.y * DT, accB.z * DT, accB.w * DT);
}

extern "C" void kernel_launch(void* const* d_in, const int* in_sizes, int n_in,
                              void* d_out, int out_size, void* d_ws, size_t ws_size,
                              hipStream_t stream) {
    const float* vol    = (const float*)d_in[0];
    const float* angles = (const float*)d_in[1];
    float* out          = (float*)d_out;

    const size_t need_full = VOLP_BYTES + SEGS * SINO * sizeof(float);  // ~18.2 MB
    const int pad_blocks = (int)((VOLP_COLS * 16 + 255) / 256);

    if (ws_size >= VOLP_BYTES) {
        unsigned int* volp = (unsigned int*)d_ws;
        hipLaunchKernelGGL(vol_pad_f16, dim3(pad_blocks), dim3(256), 0, stream, vol, volp);
        if (ws_size >= need_full) {
            float* partial = (float*)((char*)d_ws + VOLP_BYTES);
            dim3 grid(U_N / RAYS_PER_BLOCK, A_N, SEGS);   // 16 x 96 x 2 = 3072 blocks
            hipLaunchKernelGGL(joseph_fwd_inc, grid, dim3(BLOCK_THREADS), 0, stream,
                               (const unsigned short*)volp, angles, partial, 1.0f);
            hipLaunchKernelGGL(reduce_segs2, dim3(SINO / 4 / 256), dim3(256), 0, stream,
                               (const float4*)partial, (float4*)out);
        } else {
            dim3 grid(U_N / RAYS_PER_BLOCK, A_N, 1);
            hipLaunchKernelGGL(joseph_fwd_inc, grid, dim3(BLOCK_THREADS), 0, stream,
                               (const unsigned short*)volp, angles, out, DT);
        }
    } else {
        dim3 grid(U_N / 16, A_N);
        hipLaunchKernelGGL(joseph_fwd_f32, grid, dim3(256), 0, stream, vol, angles, out);
    }
}

// Round 15
// 111.642 us; speedup vs baseline: 1.0464x; 1.0464x over previous
//
#include <hip/hip_runtime.h>
#include <hip/hip_fp16.h>

namespace {
constexpr int A_N = 96;
constexpr int U_N = 128;
constexpr int V_N = 128;
constexpr int W_N = 128;
constexpr int H_N = 128;
constexpr int NSTEPS = 128;
constexpr float T_HALF = 89.80256121069154f;
constexpr float DT = 1.4031650189170554f;   // 2*T/NSTEPS
constexpr float INV_DT = 1.0f / DT;
constexpr int PAD = 6;                      // zero border: covers range slop + unroll alignment
constexpr int WP = W_N + 2 * PAD;           // 140 padded columns per row
constexpr int ROW_BYTES = WP * 256;         // x-stride in bytes (f16 column = 256 B)
constexpr int RAYS_PER_BLOCK = 8;           // 128-thread blocks
constexpr int BLOCK_THREADS = RAYS_PER_BLOCK * 16;
constexpr int SEGS = 2;
constexpr size_t VOLP_COLS = (size_t)WP * WP;          // 19600 columns
constexpr size_t VOLP_BYTES = VOLP_COLS * 256;         // ~5.02 MB
constexpr size_t SINO = (size_t)U_N * A_N * V_N;       // 1.57M floats
}

// ---- pack two floats -> half2 bits ----
__device__ __forceinline__ unsigned int packh2(float a, float b) {
    return (unsigned int)__half_as_ushort(__float2half_rn(a)) |
           ((unsigned int)__half_as_ushort(__float2half_rn(b)) << 16);
}

// ---- pre-pass: fp32 volume -> padded f16 volume (zero border of PAD cols) ----
__global__ __launch_bounds__(256) void vol_pad_f16(
    const float* __restrict__ vol, unsigned int* __restrict__ volp)
{
    const int idx = blockIdx.x * 256 + threadIdx.x;    // WP*WP*16 threads
    if (idx >= (int)(VOLP_COLS * 16)) return;
    const int zo  = idx & 15;
    const int col = idx >> 4;
    const int yp = col % WP;
    const int xp = col / WP;
    const int x = xp - PAD;
    const int y = yp - PAD;
    uint4 o = make_uint4(0u, 0u, 0u, 0u);
    if ((unsigned)x < 128u && (unsigned)y < 128u) {
        const float* src = vol + (((size_t)x * 128 + y) << 7) + zo * 8;
        const float4 f0 = *(const float4*)(src);
        const float4 f1 = *(const float4*)(src + 4);
        o.x = packh2(f0.x, f0.y);
        o.y = packh2(f0.z, f0.w);
        o.z = packh2(f1.x, f1.y);
        o.w = packh2(f1.z, f1.w);
    }
    *(uint4*)((char*)volp + (size_t)col * 256 + zo * 16) = o;
}

// ---- one bilinear step: returns base pointer for step i (no bounds checks) ----
__device__ __forceinline__ const char* step_base(
    const char* volc, int lane16, float i_f, float cv, float sv, float xb, float yb,
    float& fx, float& fy)
{
    const float tf = fmaf(i_f + 0.5f, DT, -T_HALF);
    const float xi = fmaf(tf, cv, xb);
    const float yi = fmaf(tf, sv, yb);
    const float fx0 = floorf(xi);
    const float fy0 = floorf(yi);
    fx = xi - fx0;
    fy = yi - fy0;
    const int x0 = (int)fx0;
    const int y0 = (int)fy0;
    const int base = (((x0 + PAD) * WP + (y0 + PAD)) << 8) + lane16;
    return volc + base;
}

__device__ __forceinline__ void consume(
    const uint4& q00, const uint4& q01, const uint4& q10, const uint4& q11,
    float fx, float fy, float* accf)
{
    const float wx0 = 1.f - fx;
    const float wy0 = 1.f - fy;
    const __half2 w00 = __float2half2_rn(wx0 * wy0);  // (x0,y0)
    const __half2 w01 = __float2half2_rn(wx0 * fy);   // (x0,y1)
    const __half2 w10 = __float2half2_rn(fx  * wy0);  // (x1,y0)
    const __half2 w11 = __float2half2_rn(fx  * fy);   // (x1,y1)
    const __half2* h00 = (const __half2*)&q00;
    const __half2* h01 = (const __half2*)&q01;
    const __half2* h10 = (const __half2*)&q10;
    const __half2* h11 = (const __half2*)&q11;
#pragma unroll
    for (int j = 0; j < 4; ++j) {
        __half2 p = __hmul2(w00, h00[j]);
        p = __hfma2(w01, h01[j], p);
        p = __hfma2(w10, h10[j], p);
        p = __hfma2(w11, h11[j], p);
        const float2 f = __half22float2(p);
        accf[2 * j]     += f.x;
        accf[2 * j + 1] += f.y;
    }
}

// ---- main projector: barrier-free, padded f16 volume, 2-step unrolled (8 loads in flight) ----
__global__ __launch_bounds__(BLOCK_THREADS) void joseph_fwd_inc(
    const unsigned short* __restrict__ volp,
    const float* __restrict__ angles,
    float* __restrict__ dst, float scale)
{
    const int zo  = threadIdx.x & 15;        // 16 z-groups of 8
    const int r   = threadIdx.x >> 4;        // ray in block
    const int u_i = blockIdx.x * RAYS_PER_BLOCK + r;
    const int a   = blockIdx.y;

    const int spseg = NSTEPS / gridDim.z;
    const int i0 = blockIdx.z * spseg;
    const int i1 = i0 + spseg;

    const float ang = angles[a];
    const float cv = cosf(ang);
    const float sv = sinf(ang);
    const float up = (float)u_i - 63.5f;
    const float xb = fmaf(-up, sv, 63.5f);
    const float yb = fmaf( up, cv, 63.5f);

    // valid-step range: xi,yi in (-1,128); +-2-step slop + 1 alignment step < PAD=6
    float tlo = -2.f * T_HALF, thi = 2.f * T_HALF;
    if (fabsf(cv) > 1e-6f) {
        const float ta = (-1.f - xb) / cv, tb = (128.f - xb) / cv;
        tlo = fmaxf(tlo, fminf(ta, tb));
        thi = fminf(thi, fmaxf(ta, tb));
    } else if (xb <= -1.f || xb >= 128.f) { thi = tlo - 1.f; }
    if (fabsf(sv) > 1e-6f) {
        const float ta = (-1.f - yb) / sv, tb = (128.f - yb) / sv;
        tlo = fmaxf(tlo, fminf(ta, tb));
        thi = fminf(thi, fmaxf(ta, tb));
    } else if (yb <= -1.f || yb >= 128.f) { thi = tlo - 1.f; }
    const int ilo = (int)floorf(fmaf(tlo + T_HALF, INV_DT, -0.5f)) - 1;
    const int ihi = (int)ceilf (fmaf(thi + T_HALF, INV_DT, -0.5f)) + 1;
    int lo = min(max(ilo, i0), i1);
    int hi = min(max(ihi + 1, i0), i1);
    lo &= ~1;                                  // even-align down (pad-safe)
    hi = (hi + 1) & ~1;                        // even-align up (spseg even -> hi<=i1)

    const char* __restrict__ volc = (const char*)volp;
    const int lane16 = zo << 4;

    float accf[8];
#pragma unroll
    for (int k = 0; k < 8; ++k) accf[k] = 0.f;

    for (int i = lo; i < hi; i += 2) {
        float fxA, fyA, fxB, fyB;
        const char* pA = step_base(volc, lane16, (float)i,       cv, sv, xb, yb, fxA, fyA);
        const char* pB = step_base(volc, lane16, (float)(i + 1), cv, sv, xb, yb, fxB, fyB);

        // issue all 8 loads before consuming any
        const uint4 qA00 = *(const uint4*)(pA);
        const uint4 qA01 = *(const uint4*)(pA + 256);
        const uint4 qA10 = *(const uint4*)(pA + ROW_BYTES);
        const uint4 qA11 = *(const uint4*)(pA + ROW_BYTES + 256);
        const uint4 qB00 = *(const uint4*)(pB);
        const uint4 qB01 = *(const uint4*)(pB + 256);
        const uint4 qB10 = *(const uint4*)(pB + ROW_BYTES);
        const uint4 qB11 = *(const uint4*)(pB + ROW_BYTES + 256);

        consume(qA00, qA01, qA10, qA11, fxA, fyA, accf);
        consume(qB00, qB01, qB10, qB11, fxB, fyB, accf);
    }

    float* op = dst + (size_t)blockIdx.z * SINO + ((size_t)u_i * A_N + a) * V_N + 8 * zo;
    *(float4*)(op)     = make_float4(accf[0] * scale, accf[1] * scale, accf[2] * scale, accf[3] * scale);
    *(float4*)(op + 4) = make_float4(accf[4] * scale, accf[5] * scale, accf[6] * scale, accf[7] * scale);
}

// ---- reduce: out = (p0+p1) * DT ----
__global__ __launch_bounds__(256) void reduce_segs2(
    const float4* __restrict__ p, float4* __restrict__ out)
{
    const size_t i = (size_t)blockIdx.x * 256 + threadIdx.x;  // SINO/4 threads
    const size_t q = SINO / 4;
    const float4 a = p[i];
    const float4 b = p[i + q];
    out[i] = make_float4((a.x + b.x) * DT, (a.y + b.y) * DT,
                         (a.z + b.z) * DT, (a.w + b.w) * DT);
}

// ---- fallback: fp32 volume, no workspace needed ----
__global__ __launch_bounds__(256) void joseph_fwd_f32(
    const float* __restrict__ vol,
    const float* __restrict__ angles,
    float* __restrict__ out)
{
    const int zo  = threadIdx.x & 15;
    const int r   = threadIdx.x >> 4;
    const int u_i = blockIdx.x * 16 + r;
    const int a   = blockIdx.y;

    const float ang = angles[a];
    const float c = cosf(ang);
    const float s = sinf(ang);
    const float u = (float)u_i - 63.5f;
    const float xb = fmaf(-u, s, 63.5f);
    const float yb = fmaf( u, c, 63.5f);

    const float* volz = vol + 8 * zo;
    float4 accA = make_float4(0.f, 0.f, 0.f, 0.f);
    float4 accB = make_float4(0.f, 0.f, 0.f, 0.f);

    for (int i = 0; i < NSTEPS; ++i) {
        const float t  = fmaf((float)i + 0.5f, DT, -T_HALF);
        const float xi = fmaf(t, c, xb);
        const float yi = fmaf(t, s, yb);
        const float fx0f = floorf(xi);
        const float fy0f = floorf(yi);
        const int x0 = (int)fx0f;
        const int y0 = (int)fy0f;
        const float fx = xi - fx0f;
        const float fy = yi - fy0f;
        const int x1 = x0 + 1;
        const int y1 = y0 + 1;
        const float wx0 = (x0 >= 0 && x0 < W_N) ? (1.f - fx) : 0.f;
        const float wx1 = (x1 >= 0 && x1 < W_N) ? fx : 0.f;
        const float wy0 = (y0 >= 0 && y0 < H_N) ? (1.f - fy) : 0.f;
        const float wy1 = (y1 >= 0 && y1 < H_N) ? fy : 0.f;
        if ((wx0 + wx1) == 0.f || (wy0 + wy1) == 0.f) continue;
        const int cx0 = min(max(x0, 0), W_N - 1);
        const int cx1 = min(max(x1, 0), W_N - 1);
        const int cy0 = min(max(y0, 0), H_N - 1);
        const int cy1 = min(max(y1, 0), H_N - 1);
        const float* p00 = volz + ((cx0 * H_N + cy0) << 7);
        const float* p01 = volz + ((cx1 * H_N + cy0) << 7);
        const float* p10 = volz + ((cx0 * H_N + cy1) << 7);
        const float* p11 = volz + ((cx1 * H_N + cy1) << 7);
        const float4 v00a = *(const float4*)(p00);
        const float4 v00b = *(const float4*)(p00 + 4);
        const float4 v01a = *(const float4*)(p01);
        const float4 v01b = *(const float4*)(p01 + 4);
        const float4 v10a = *(const float4*)(p10);
        const float4 v10b = *(const float4*)(p10 + 4);
        const float4 v11a = *(const float4*)(p11);
        const float4 v11b = *(const float4*)(p11 + 4);
        const float w00 = wx0 * wy0, w01 = wx1 * wy0, w10 = wx0 * wy1, w11 = wx1 * wy1;
        accA.x = fmaf(w00, v00a.x, fmaf(w01, v01a.x, fmaf(w10, v10a.x, fmaf(w11, v11a.x, accA.x))));
        accA.y = fmaf(w00, v00a.y, fmaf(w01, v01a.y, fmaf(w10, v10a.y, fmaf(w11, v11a.y, accA.y))));
        accA.z = fmaf(w00, v00a.z, fmaf(w01, v01a.z, fmaf(w10, v10a.z, fmaf(w11, v11a.z, accA.z))));
        accA.w = fmaf(w00, v00a.w, fmaf(w01, v01a.w, fmaf(w10, v10a.w, fmaf(w11, v11a.w, accA.w))));
        accB.x = fmaf(w00, v00b.x, fmaf(w01, v01b.x, fmaf(w10, v10b.x, fmaf(w11, v11b.x, accB.x))));
        accB.y = fmaf(w00, v00b.y, fmaf(w01, v01b.y, fmaf(w10, v10b.y, fmaf(w11, v11b.y, accB.y))));
        accB.z = fmaf(w00, v00b.z, fmaf(w01, v01b.z, fmaf(w10, v10b.z, fmaf(w11, v11b.z, accB.z))));
        accB.w = fmaf(w00, v00b.w, fmaf(w01, v01b.w, fmaf(w10, v10b.w, fmaf(w11, v11b.w, accB.w))));
    }

    float* op = out + ((size_t)u_i * A_N + a) * V_N + 8 * zo;
    *(float4*)(op)     = make_float4(accA.x * DT, accA.y * DT, accA.z * DT, accA.w * DT);
    *(float4*)(op + 4) = make_float4(accB.x * DT, accB.y * DT, accB.z * DT, accB.w * DT);
}

extern "C" void kernel_launch(void* const* d_in, const int* in_sizes, int n_in,
                              void* d_out, int out_size, void* d_ws, size_t ws_size,
                              hipStream_t stream) {
    const float* vol    = (const float*)d_in[0];
    const float* angles = (const float*)d_in[1];
    float* out          = (float*)d_out;

    const size_t need_full = VOLP_BYTES + SEGS * SINO * sizeof(float);
    const int pad_blocks = (int)((VOLP_COLS * 16 + 255) / 256);

    if (ws_size >= VOLP_BYTES) {
        unsigned int* volp = (unsigned int*)d_ws;
        hipLaunchKernelGGL(vol_pad_f16, dim3(pad_blocks), dim3(256), 0, stream, vol, volp);
        if (ws_size >= need_full) {
            float* partial = (float*)((char*)d_ws + VOLP_BYTES);
            dim3 grid(U_N / RAYS_PER_BLOCK, A_N, SEGS);   // 16 x 96 x 2 = 3072 blocks
            hipLaunchKernelGGL(joseph_fwd_inc, grid, dim3(BLOCK_THREADS), 0, stream,
                               (const unsigned short*)volp, angles, partial, 1.0f);
            hipLaunchKernelGGL(reduce_segs2, dim3(SINO / 4 / 256), dim3(256), 0, stream,
                               (const float4*)partial, (float4*)out);
        } else {
            dim3 grid(U_N / RAYS_PER_BLOCK, A_N, 1);
            hipLaunchKernelGGL(joseph_fwd_inc, grid, dim3(BLOCK_THREADS), 0, stream,
                               (const unsigned short*)volp, angles, out, DT);
        }
    } else {
        dim3 grid(U_N / 16, A_N);
        hipLaunchKernelGGL(joseph_fwd_f32, grid, dim3(256), 0, stream, vol, angles, out);
    }
}